// Round 1
// baseline (3909.048 us; speedup 1.0000x reference)
//
#include <hip/hip_runtime.h>
#include <hip/hip_bf16.h>

#define CC   64
#define SHOT 16
#define DD   320
#define ND   1008            // (CC-1)*SHOT
#define MS   (CC * SHOT)     // 1024
#define MD   (CC * ND)       // 64512
#define LN_EPS 1e-5f

// ---------------------------------------------------------------------------
// Generic 64x64-tile fp32 GEMM:  Out[M x 320] = Asrc[M x 320] @ W[320 x 320]
//   mode 0: A from pointer      mode 1: A[m][k] = xmean[c][k] - x[row(m)][k]
//   mode 2: A[m][k] = x[m][k] - xmean[m/16][k]
// epilogue: + bias[n]  (optional) - meanSub[(m/rpc)][n]  (optional) + Res[m][n]
// ---------------------------------------------------------------------------
__global__ __launch_bounds__(256) void gemm_ep(
    const float* __restrict__ A, const float* __restrict__ Xg,
    const float* __restrict__ Xmean, const int mode, const int c0,
    const float* __restrict__ W, const float* __restrict__ bias,
    float* __restrict__ Out, const float* __restrict__ meanSub, const int rpc,
    const float* __restrict__ Res)
{
    __shared__ float As[16][68];   // [k][m], pad 68 (16B-aligned rows, 2-way max)
    __shared__ float Bs[16][68];   // [k][n]
    const int t  = threadIdx.x;
    const int m0 = blockIdx.x * 64;
    const int n0 = blockIdx.y * 64;
    const int tm = t >> 4, tn = t & 15;
    const int la = t >> 2, ka = (t & 3) * 4;   // A-tile loader: row la, k-quad ka
    const int kb = t >> 4, nb = (t & 15) * 4;  // B-tile loader

    // hoist gather addressing (row fixed per thread across the K loop)
    const int am = m0 + la;
    const float* aptr;
    const float* mptr = nullptr;
    if (mode == 0) {
        aptr = A + (size_t)am * DD;
    } else if (mode == 1) {
        const int lc = am / ND;
        const int j  = am - lc * ND;
        const int c  = c0 + lc;
        const int oi = j >> 4, s = j & 15;
        const int oc = (oi < c) ? oi : oi + 1;
        aptr = Xg + (size_t)(oc * SHOT + s) * DD;  // subtrahend
        mptr = Xmean + (size_t)c * DD;             // minuend
    } else {
        aptr = Xg + (size_t)am * DD;
        mptr = Xmean + (size_t)(am >> 4) * DD;
    }

    float acc[4][4] = {};
    for (int k0 = 0; k0 < DD; k0 += 16) {
        float4 av = *reinterpret_cast<const float4*>(aptr + k0 + ka);
        if (mode == 1) {
            const float4 mv = *reinterpret_cast<const float4*>(mptr + k0 + ka);
            av.x = mv.x - av.x; av.y = mv.y - av.y; av.z = mv.z - av.z; av.w = mv.w - av.w;
        } else if (mode == 2) {
            const float4 mv = *reinterpret_cast<const float4*>(mptr + k0 + ka);
            av.x -= mv.x; av.y -= mv.y; av.z -= mv.z; av.w -= mv.w;
        }
        const float4 bv = *reinterpret_cast<const float4*>(&W[(size_t)(k0 + kb) * DD + n0 + nb]);
        As[ka + 0][la] = av.x;
        As[ka + 1][la] = av.y;
        As[ka + 2][la] = av.z;
        As[ka + 3][la] = av.w;
        *reinterpret_cast<float4*>(&Bs[kb][nb]) = bv;
        __syncthreads();
        #pragma unroll
        for (int k = 0; k < 16; ++k) {
            const float4 a = *reinterpret_cast<const float4*>(&As[k][tm * 4]);
            const float4 b = *reinterpret_cast<const float4*>(&Bs[k][tn * 4]);
            const float a4[4] = {a.x, a.y, a.z, a.w};
            const float b4[4] = {b.x, b.y, b.z, b.w};
            #pragma unroll
            for (int i = 0; i < 4; ++i)
                #pragma unroll
                for (int j = 0; j < 4; ++j)
                    acc[i][j] += a4[i] * b4[j];
        }
        __syncthreads();
    }

    const float4 bb = *reinterpret_cast<const float4*>(&bias[n0 + tn * 4]);
    const float bb4[4] = {bb.x, bb.y, bb.z, bb.w};
    #pragma unroll
    for (int i = 0; i < 4; ++i) {
        const int m = m0 + tm * 4 + i;
        const size_t ro = (size_t)m * DD + n0 + tn * 4;
        float v4[4];
        #pragma unroll
        for (int j = 0; j < 4; ++j) v4[j] = acc[i][j] + bb4[j];
        if (meanSub) {
            const int cm = m / rpc;
            const float4 mm = *reinterpret_cast<const float4*>(&meanSub[(size_t)cm * DD + n0 + tn * 4]);
            v4[0] -= mm.x; v4[1] -= mm.y; v4[2] -= mm.z; v4[3] -= mm.w;
        }
        if (Res) {
            const float4 rr = *reinterpret_cast<const float4*>(&Res[ro]);
            v4[0] += rr.x; v4[1] += rr.y; v4[2] += rr.z; v4[3] += rr.w;
        }
        *reinterpret_cast<float4*>(&Out[ro]) = make_float4(v4[0], v4[1], v4[2], v4[3]);
    }
}

// ---------------------------------------------------------------------------
// Flash attention, per-class, BQ=BK=16, online softmax, O = softmax(QK^T/s)V.
// Layouts are [class][row][d] with rowsPerClass rows. grid = nClasses * (rows/16).
// thread (qr,g): computes S[qr][g]; owns O[qr][g*4 + 64*i], i<5.
// ---------------------------------------------------------------------------
__global__ __launch_bounds__(256) void flash_attn(
    const float* __restrict__ Q, const float* __restrict__ K,
    const float* __restrict__ V, float* __restrict__ O, const int rowsPerClass)
{
    const int qtPer = rowsPerClass >> 4;
    int bx = blockIdx.x;
    const int nwg = gridDim.x;
    if ((nwg & 7) == 0) {                 // XCD-chunked swizzle (bijective: nwg%8==0)
        const int chunk = nwg >> 3;
        bx = (bx & 7) * chunk + (bx >> 3);
    }
    const int c  = bx / qtPer;
    const int qt = bx - c * qtPer;
    const size_t base = (size_t)c * rowsPerClass * DD;
    const float* Qc = Q + base + (size_t)qt * 16 * DD;
    const float* Kc = K + base;
    const float* Vc = V + base;
    float* Oc = O + base + (size_t)qt * 16 * DD;

    __shared__ float Qs[16][324];
    __shared__ float Ks[16][324];
    __shared__ float Vs[16][324];

    const int t = threadIdx.x;
    #pragma unroll
    for (int i = 0; i < 5; ++i) {
        const int flat = t + i * 256;
        const int r = flat / 80, kq = (flat - r * 80) * 4;
        *reinterpret_cast<float4*>(&Qs[r][kq]) =
            *reinterpret_cast<const float4*>(&Qc[r * DD + kq]);
    }
    const int qr = t >> 4, g = t & 15;
    const int base16 = t & 48;            // group base within the wave
    float mrun = -1e30f, l = 0.f;
    float acc[20];
    #pragma unroll
    for (int i = 0; i < 20; ++i) acc[i] = 0.f;
    const float scale = 0.055901699437494740f;  // 1/sqrt(320)

    const int nKT = rowsPerClass >> 4;
    for (int kt = 0; kt < nKT; ++kt) {
        __syncthreads();
        #pragma unroll
        for (int i = 0; i < 5; ++i) {
            const int flat = t + i * 256;
            const int r = flat / 80, kq = (flat - r * 80) * 4;
            *reinterpret_cast<float4*>(&Ks[r][kq]) =
                *reinterpret_cast<const float4*>(&Kc[(kt * 16 + r) * DD + kq]);
            *reinterpret_cast<float4*>(&Vs[r][kq]) =
                *reinterpret_cast<const float4*>(&Vc[(kt * 16 + r) * DD + kq]);
        }
        __syncthreads();
        float s = 0.f;
        #pragma unroll 16
        for (int k = 0; k < DD; k += 4) {
            const float4 qv = *reinterpret_cast<const float4*>(&Qs[qr][k]);
            const float4 kv = *reinterpret_cast<const float4*>(&Ks[g][k]);
            s += qv.x * kv.x + qv.y * kv.y + qv.z * kv.z + qv.w * kv.w;
        }
        s *= scale;
        float rmax = s;
        #pragma unroll
        for (int off = 1; off < 16; off <<= 1)
            rmax = fmaxf(rmax, __shfl_xor(rmax, off));
        const float newm = fmaxf(mrun, rmax);
        const float p = __expf(s - newm);
        float rsum = p;
        #pragma unroll
        for (int off = 1; off < 16; off <<= 1)
            rsum += __shfl_xor(rsum, off);
        const float alpha = __expf(mrun - newm);
        l = l * alpha + rsum;
        mrun = newm;
        #pragma unroll
        for (int i = 0; i < 20; ++i) acc[i] *= alpha;
        #pragma unroll
        for (int kr = 0; kr < 16; ++kr) {
            const float pk = __shfl(p, base16 + kr);
            #pragma unroll
            for (int i = 0; i < 5; ++i) {
                const float4 vv = *reinterpret_cast<const float4*>(&Vs[kr][g * 4 + 64 * i]);
                acc[i * 4 + 0] += pk * vv.x;
                acc[i * 4 + 1] += pk * vv.y;
                acc[i * 4 + 2] += pk * vv.z;
                acc[i * 4 + 3] += pk * vv.w;
            }
        }
    }
    const float invl = 1.f / l;
    #pragma unroll
    for (int i = 0; i < 5; ++i) {
        *reinterpret_cast<float4*>(&Oc[qr * DD + g * 4 + 64 * i]) =
            make_float4(acc[i * 4 + 0] * invl, acc[i * 4 + 1] * invl,
                        acc[i * 4 + 2] * invl, acc[i * 4 + 3] * invl);
    }
}

// ---------------------------------------------------------------------------
// Per-row LayerNorm + logit:  logits[m] = LN(X[m]) . Wout + bout.  1 wave/row.
// ---------------------------------------------------------------------------
__global__ __launch_bounds__(256) void ln_logit(
    const float* __restrict__ X, const float* __restrict__ gam,
    const float* __restrict__ bet, const float* __restrict__ Wout,
    const float* __restrict__ bout, float* __restrict__ logits, const int M)
{
    const int row = blockIdx.x * 4 + (threadIdx.x >> 6);
    if (row >= M) return;
    const int lane = threadIdx.x & 63;
    const float* x = X + (size_t)row * DD;
    float v[5];
    float s = 0.f;
    #pragma unroll
    for (int i = 0; i < 5; ++i) { v[i] = x[lane + 64 * i]; s += v[i]; }
    #pragma unroll
    for (int off = 32; off; off >>= 1) s += __shfl_xor(s, off);
    const float mu = s * (1.f / DD);
    float q = 0.f;
    #pragma unroll
    for (int i = 0; i < 5; ++i) { const float d = v[i] - mu; q += d * d; }
    #pragma unroll
    for (int off = 32; off; off >>= 1) q += __shfl_xor(q, off);
    const float inv = rsqrtf(q * (1.f / DD) + LN_EPS);
    float lg = 0.f;
    #pragma unroll
    for (int i = 0; i < 5; ++i) {
        const int k = lane + 64 * i;
        lg += (gam[k] * (v[i] - mu) * inv + bet[k]) * Wout[k];
    }
    #pragma unroll
    for (int off = 32; off; off >>= 1) lg += __shfl_xor(lg, off);
    if (lane == 0) logits[row] = lg + bout[0];
}

// ---------------------------------------------------------------------------
// Per-class: softmax over 16 same-logits and 1008 diff-logits, then
// out[c][d] = (sum_i w_s[i]*Ps[c,i,d] + sum_j w_d[j]*Pd[c,j,d]) / 1024
// ---------------------------------------------------------------------------
__global__ __launch_bounds__(320) void final_reduce(
    const float* __restrict__ logits_s, const float* __restrict__ logits_d,
    const float* __restrict__ Ps, const float* __restrict__ Pd,
    float* __restrict__ out)
{
    const int c = blockIdx.x;
    const int t = threadIdx.x;
    __shared__ float w[16 + ND];
    __shared__ float red[5];
    if (t < 16) w[t] = logits_s[c * 16 + t];
    for (int j = t; j < ND; j += 320) w[16 + j] = logits_d[c * ND + j];
    __syncthreads();
    if (t == 0) {                       // tiny 16-way softmax: serial on one lane
        float mx = w[0];
        #pragma unroll
        for (int i = 1; i < 16; ++i) mx = fmaxf(mx, w[i]);
        float ssum = 0.f;
        #pragma unroll
        for (int i = 0; i < 16; ++i) { const float e = __expf(w[i] - mx); w[i] = e; ssum += e; }
        const float inv = 1.f / ssum;
        #pragma unroll
        for (int i = 0; i < 16; ++i) w[i] *= inv;
    }
    float lm = -1e30f;
    for (int j = t; j < ND; j += 320) lm = fmaxf(lm, w[16 + j]);
    #pragma unroll
    for (int off = 32; off; off >>= 1) lm = fmaxf(lm, __shfl_xor(lm, off));
    if ((t & 63) == 0) red[t >> 6] = lm;
    __syncthreads();
    const float mx = fmaxf(fmaxf(fmaxf(red[0], red[1]), fmaxf(red[2], red[3])), red[4]);
    float ls = 0.f;
    for (int j = t; j < ND; j += 320) { const float e = __expf(w[16 + j] - mx); w[16 + j] = e; ls += e; }
    #pragma unroll
    for (int off = 32; off; off >>= 1) ls += __shfl_xor(ls, off);
    __syncthreads();                    // all reads of red done before reuse
    if ((t & 63) == 0) red[t >> 6] = ls;
    __syncthreads();
    const float inv = 1.f / (red[0] + red[1] + red[2] + red[3] + red[4]);
    for (int j = t; j < ND; j += 320) w[16 + j] *= inv;
    __syncthreads();
    float acc = 0.f;
    const float* Psc = Ps + (size_t)c * SHOT * DD + t;
    const float* Pdc = Pd + (size_t)c * ND * DD + t;
    #pragma unroll 4
    for (int i = 0; i < 16; ++i) acc += w[i] * Psc[(size_t)i * DD];
    for (int j = 0; j < ND; ++j) acc += w[16 + j] * Pdc[(size_t)j * DD];
    out[c * DD + t] = acc * (1.f / 1024.f);
}

// ---------------------------------------------------------------------------
extern "C" void kernel_launch(void* const* d_in, const int* in_sizes, int n_in,
                              void* d_out, int out_size, void* d_ws, size_t ws_size,
                              hipStream_t stream)
{
    const float* xmean = (const float*)d_in[0];
    const float* x     = (const float*)d_in[1];
    const float* Wsame = (const float*)d_in[2];
    const float* bsame = (const float*)d_in[3];
    const float* Wdiff = (const float*)d_in[4];
    const float* bdiff = (const float*)d_in[5];
    const float* Wq    = (const float*)d_in[6];
    const float* bq    = (const float*)d_in[7];
    const float* Wk    = (const float*)d_in[8];
    const float* bk    = (const float*)d_in[9];
    const float* Wv    = (const float*)d_in[10];
    const float* bv    = (const float*)d_in[11];
    const float* Wfc   = (const float*)d_in[12];
    const float* bfc   = (const float*)d_in[13];
    const float* lng   = (const float*)d_in[14];
    const float* lnb   = (const float*)d_in[15];
    const float* Wout  = (const float*)d_in[16];
    const float* boutp = (const float*)d_in[17];
    float* outp = (float*)d_out;

    float* ws = (float*)d_ws;
    size_t off = 0;
    auto alloc = [&](size_t n) { float* p = ws + off; off += n; return p; };

    const size_t MSD = (size_t)MS * DD;
    float* Pd   = alloc((size_t)MD * DD);   // P_diff, full (needed by final_reduce)
    float* Ps   = alloc(MSD);
    float* Qs   = alloc(MSD);               // also reused as FC_same output
    float* Ks   = alloc(MSD);
    float* Vs   = alloc(MSD);
    float* Os   = alloc(MSD);
    float* logd = alloc(MD);
    float* logs = alloc(MS);

    // class-chunk so the 4 diff-branch scratch buffers fit ws_size.
    // CB must keep CB*1008 divisible by 64 -> CB in {64,32,16,8,4}.
    int CB = 64;
    while (CB > 4) {
        const size_t need = (off + 4 * (size_t)CB * ND * DD) * sizeof(float);
        if (need <= ws_size) break;
        CB >>= 1;
    }
    float* Qc = alloc((size_t)CB * ND * DD);  // Q_diff chunk, reused as FC output
    float* Kc = alloc((size_t)CB * ND * DD);
    float* Vc = alloc((size_t)CB * ND * DD);
    float* Oc = alloc((size_t)CB * ND * DD);

    const dim3 blk(256);
    // ---- same branch (tiny: M=1024) ----
    {
        const dim3 g(MS / 64, DD / 64);
        gemm_ep<<<g, blk, 0, stream>>>(nullptr, x, xmean, 2, 0, Wsame, bsame, Ps, xmean, SHOT, nullptr);
        gemm_ep<<<g, blk, 0, stream>>>(Ps, nullptr, nullptr, 0, 0, Wq, bq, Qs, nullptr, 1, nullptr);
        gemm_ep<<<g, blk, 0, stream>>>(Ps, nullptr, nullptr, 0, 0, Wk, bk, Ks, nullptr, 1, nullptr);
        gemm_ep<<<g, blk, 0, stream>>>(Ps, nullptr, nullptr, 0, 0, Wv, bv, Vs, nullptr, 1, nullptr);
        flash_attn<<<CC, blk, 0, stream>>>(Qs, Ks, Vs, Os, SHOT);
        gemm_ep<<<g, blk, 0, stream>>>(Os, nullptr, nullptr, 0, 0, Wfc, bfc, Qs, nullptr, 1, Ps);
        ln_logit<<<MS / 4, blk, 0, stream>>>(Qs, lng, lnb, Wout, boutp, logs, MS);
    }
    // ---- diff branch, chunked over classes ----
    for (int c0 = 0; c0 < CC; c0 += CB) {
        const int Mch = CB * ND;
        float* Pch = Pd + (size_t)c0 * ND * DD;
        const dim3 g(Mch / 64, DD / 64);
        gemm_ep<<<g, blk, 0, stream>>>(nullptr, x, xmean, 1, c0, Wdiff, bdiff, Pch,
                                       xmean + (size_t)c0 * DD, ND, nullptr);
        gemm_ep<<<g, blk, 0, stream>>>(Pch, nullptr, nullptr, 0, 0, Wq, bq, Qc, nullptr, 1, nullptr);
        gemm_ep<<<g, blk, 0, stream>>>(Pch, nullptr, nullptr, 0, 0, Wk, bk, Kc, nullptr, 1, nullptr);
        gemm_ep<<<g, blk, 0, stream>>>(Pch, nullptr, nullptr, 0, 0, Wv, bv, Vc, nullptr, 1, nullptr);
        flash_attn<<<CB * (ND / 16), blk, 0, stream>>>(Qc, Kc, Vc, Oc, ND);
        gemm_ep<<<g, blk, 0, stream>>>(Oc, nullptr, nullptr, 0, 0, Wfc, bfc, Qc, nullptr, 1, Pch);
        ln_logit<<<Mch / 4, blk, 0, stream>>>(Qc, lng, lnb, Wout, boutp, logd + (size_t)c0 * ND, Mch);
    }
    final_reduce<<<CC, dim3(320), 0, stream>>>(logs, logd, Ps, Pd, outp);
}

// Round 2
// 658.478 us; speedup vs baseline: 5.9365x; 5.9365x over previous
//
#include <hip/hip_runtime.h>

#define CC   64
#define SHOT 16
#define DD   320
#define ND   1008            // (CC-1)*SHOT
#define MS   (CC * SHOT)     // 1024
#define LN_EPS 1e-5f

typedef __attribute__((ext_vector_type(8))) short short8;    // 8 bf16 = 4 VGPR (MFMA A/B frag)
typedef __attribute__((ext_vector_type(4))) float floatx4;   // MFMA C/D frag
typedef __attribute__((ext_vector_type(4))) int i32x4;

__device__ __forceinline__ unsigned short f2b(float f) {     // fp32 -> bf16 RNE
  union { float f; unsigned int u; } v; v.f = f;
  unsigned int r = v.u + 0x7FFFu + ((v.u >> 16) & 1u);
  return (unsigned short)(r >> 16);
}
__device__ __forceinline__ float b2f(unsigned short b) {
  union { unsigned int u; float f; } v; v.u = ((unsigned int)b) << 16; return v.f;
}
__device__ __forceinline__ unsigned int pk2(float a, float b) {
  return (unsigned int)f2b(a) | ((unsigned int)f2b(b) << 16);
}
__device__ __forceinline__ void gl_lds16(const void* g, void* l) {
  __builtin_amdgcn_global_load_lds(
      (const __attribute__((address_space(1))) unsigned int*)g,
      (__attribute__((address_space(3))) unsigned int*)l, 16, 0, 0);
}
__device__ __forceinline__ floatx4 mfma16(short8 a, short8 b, floatx4 c) {
  return __builtin_amdgcn_mfma_f32_16x16x32_bf16(a, b, c, 0, 0, 0);
}

// ---------------------------------------------------------------------------
// MFMA GEMM: Out[M x 320] = A[M x 320] @ W[320 x 320]   (A bf16 or fp32-gather)
// BM=128 BN=64 BK=64, 4 waves (2x2), wave tile 64x32 (4 m-tiles x 2 n-tiles).
// Bt is W^T bf16 [320 n][320 k]. mode0: A bf16 ptr; mode1: A=xmean[c]-x[gather];
// mode2: A=x[m]-xmean[m/16]. Epilogue: +bias, -msMean[(m/msRpc)], +ResB (bf16),
// row remap mo=(m/rpcOut)*pitchOut+m%rpcOut (rpcOut==0 -> identity),
// writes OutB (bf16) and/or OutF (fp32).
// LDS tiles linear w/ XOR-chunk swizzle (write-side = pre-swizzled source).
// ---------------------------------------------------------------------------
__global__ __launch_bounds__(256, 2) void gemm_mfma(
    const unsigned short* __restrict__ A,
    const float* __restrict__ Xg, const float* __restrict__ Xmean,
    const int mode, const int c0,
    const unsigned short* __restrict__ Bt,
    const float* __restrict__ bias,
    unsigned short* __restrict__ OutB, float* __restrict__ OutF,
    const unsigned short* __restrict__ ResB,
    const float* __restrict__ msMean, const int msRpc,
    const int rpcOut, const int pitchOut)
{
  __shared__ __align__(16) unsigned short As[2][128 * 64];
  __shared__ __align__(16) unsigned short Bs[2][64 * 64];
  const int t  = threadIdx.x;
  const int m0 = blockIdx.x * 128;
  const int n0 = blockIdx.y * 64;
  const int wid = t >> 6, lane = t & 63;
  const int wm = wid >> 1, wn = wid & 1;
  const int l15 = lane & 15, lg = lane >> 4;

  // mode1/2 per-thread A-source row (reg-staged path): row ra, k-half kh
  const int ra = t >> 1, kh = t & 1;
  const float* aptr = nullptr; const float* mptr = nullptr;
  if (mode == 1) {
    const int am = m0 + ra;
    const int lc = am / ND, j = am - lc * ND;
    const int c  = c0 + lc;
    const int oi = j >> 4, s = j & 15;
    const int oc = (oi < c) ? oi : oi + 1;
    aptr = Xg + (size_t)(oc * SHOT + s) * DD;
    mptr = Xmean + (size_t)c * DD;
  } else if (mode == 2) {
    aptr = Xg + (size_t)(m0 + ra) * DD;
    mptr = Xmean + (size_t)((m0 + ra) >> 4) * DD;
  }

  floatx4 acc[4][2];
  #pragma unroll
  for (int i = 0; i < 4; ++i)
    #pragma unroll
    for (int j = 0; j < 2; ++j) acc[i][j] = (floatx4){0.f, 0.f, 0.f, 0.f};

  auto stage = [&](int ks, int bufi) {
    const int k0 = ks * 64;
    #pragma unroll
    for (int it = 0; it < 2; ++it) {               // B tile 64x64
      const int L = it * 256 + t;                  // 16B chunk id
      const int r = L >> 3, cs = L & 7;
      const int cl = cs ^ (r & 7);                 // pre-swizzled source chunk
      gl_lds16(Bt + (size_t)(n0 + r) * DD + k0 + cl * 8, &Bs[bufi][0] + L * 8);
    }
    if (mode == 0) {
      #pragma unroll
      for (int it = 0; it < 4; ++it) {             // A tile 128x64
        const int L = it * 256 + t;
        const int r = L >> 3, cs = L & 7;
        const int cl = cs ^ (r & 7);
        gl_lds16(A + (size_t)(m0 + r) * DD + k0 + cl * 8, &As[bufi][0] + L * 8);
      }
    } else {                                        // fp32 gather+sub+cvt, reg-staged
      const float sa = (mode == 1) ? -1.f : 1.f;
      const int kb2 = k0 + kh * 32;
      #pragma unroll
      for (int i = 0; i < 4; ++i) {
        const float4 x0  = *(const float4*)(aptr + kb2 + i * 8);
        const float4 x1  = *(const float4*)(aptr + kb2 + i * 8 + 4);
        const float4 mv0 = *(const float4*)(mptr + kb2 + i * 8);
        const float4 mv1 = *(const float4*)(mptr + kb2 + i * 8 + 4);
        i32x4 w;
        w[0] = (int)pk2(sa * (x0.x - mv0.x), sa * (x0.y - mv0.y));
        w[1] = (int)pk2(sa * (x0.z - mv0.z), sa * (x0.w - mv0.w));
        w[2] = (int)pk2(sa * (x1.x - mv1.x), sa * (x1.y - mv1.y));
        w[3] = (int)pk2(sa * (x1.z - mv1.z), sa * (x1.w - mv1.w));
        const int c  = kh * 4 + i;
        const int cw = c ^ (ra & 7);
        *(i32x4*)((char*)&As[bufi][0] + ra * 128 + cw * 16) = w;
      }
    }
  };

  auto compute = [&](int bufi) {
    #pragma unroll
    for (int kc = 0; kc < 2; ++kc) {
      short8 af[4], bf[2];
      #pragma unroll
      for (int mt = 0; mt < 4; ++mt) {
        const int row = wm * 64 + mt * 16 + l15;
        const int cs  = (kc * 4 + lg) ^ (row & 7);
        af[mt] = *(const short8*)((const char*)&As[bufi][0] + row * 128 + cs * 16);
      }
      #pragma unroll
      for (int nt = 0; nt < 2; ++nt) {
        const int row = wn * 32 + nt * 16 + l15;
        const int cs  = (kc * 4 + lg) ^ (row & 7);
        bf[nt] = *(const short8*)((const char*)&Bs[bufi][0] + row * 128 + cs * 16);
      }
      #pragma unroll
      for (int mt = 0; mt < 4; ++mt)
        #pragma unroll
        for (int nt = 0; nt < 2; ++nt)
          acc[mt][nt] = mfma16(af[mt], bf[nt], acc[mt][nt]);
    }
  };

  stage(0, 0);
  for (int ks = 0; ks < 5; ++ks) {
    __syncthreads();
    if (ks + 1 < 5) stage(ks + 1, (ks + 1) & 1);
    compute(ks & 1);
  }

  // epilogue: C[row=(lane>>4)*4+r][col=lane&15]  (m89-verified layout)
  #pragma unroll
  for (int nt = 0; nt < 2; ++nt) {
    const int n = n0 + wn * 32 + nt * 16 + l15;
    const float bb = bias[n];
    #pragma unroll
    for (int mt = 0; mt < 4; ++mt) {
      #pragma unroll
      for (int r = 0; r < 4; ++r) {
        const int m = m0 + wm * 64 + mt * 16 + lg * 4 + r;
        float v = acc[mt][nt][r] + bb;
        if (msMean) v -= msMean[(size_t)(m / msRpc) * DD + n];
        if (ResB)   v += b2f(ResB[(size_t)m * DD + n]);
        size_t mo = m;
        if (rpcOut) mo = (size_t)(m / rpcOut) * pitchOut + (m % rpcOut);
        if (OutB) OutB[mo * DD + n] = f2b(v);
        if (OutF) OutF[mo * DD + n] = v;
      }
    }
  }
}

// ---------------------------------------------------------------------------
// MFMA flash attention (swapped QK^T). Block = 4 waves, each wave owns 16
// q-rows. K-loop BK=32. S^T = mfma(K, Q); softmax reduce via shfl_xor 16/32;
// P repacked to bf16 + 8-shfl redistribution -> PV B-frag; O^T = mfma(Vt, P).
// K tile [32][320] + Vt tile [320][32] in LDS, XOR-swizzled via source addr.
// ---------------------------------------------------------------------------
__global__ __launch_bounds__(256, 2) void attn_mfma(
    const unsigned short* __restrict__ Qb, const unsigned short* __restrict__ Kb,
    const unsigned short* __restrict__ Vt, unsigned short* __restrict__ Ob,
    const int qRows, const int qPitch, const int kPitch, const int vtPitch,
    const int nKT, const int validKV, const int bpc, const int qTiles)
{
  __shared__ __align__(16) char smem[64 * 656];   // 41984B: staging 40960 + epilogue 41984
  const int t = threadIdx.x;
  const int wid = t >> 6, lane = t & 63;
  const int l15 = lane & 15, lg = lane >> 4;

  int bx = blockIdx.x;
  const int nwg = gridDim.x;
  if ((nwg & 7) == 0) bx = (bx & 7) * (nwg >> 3) + (bx >> 3);   // XCD swizzle
  const int cls  = bx / bpc;
  const int blkq = bx - cls * bpc;
  const int qt0 = blkq * 4 + wid;
  const bool wValid = qt0 < qTiles;
  const int qt = wValid ? qt0 : qTiles - 1;

  // Q fragments (B operand): lane holds Q[q=l15][kd = kc*32 + lg*8 + j]
  short8 qf[10];
  {
    const unsigned short* qrow = Qb + ((size_t)cls * qPitch + qt * 16 + l15) * DD;
    #pragma unroll
    for (int kc = 0; kc < 10; ++kc) qf[kc] = *(const short8*)(qrow + kc * 32 + lg * 8);
  }

  floatx4 o[20];
  #pragma unroll
  for (int i = 0; i < 20; ++i) o[i] = (floatx4){0.f, 0.f, 0.f, 0.f};
  float mrun = -1e30f, lsum = 0.f;
  const float scale = 0.05590169943749474f;       // 1/sqrt(320)

  for (int kt = 0; kt < nKT; ++kt) {
    // ---- stage K [32][320] and Vt [320][32], pre-swizzled source ----
    #pragma unroll
    for (int it = 0; it < 5; ++it) {
      const int L = it * 256 + t;                 // 16B chunk
      const int r = L / 40, c = L - (L / 40) * 40;
      const int cl = (c & ~7) | ((c & 7) ^ (r & 7));
      gl_lds16(Kb + ((size_t)cls * kPitch + kt * 32 + r) * DD + cl * 8, smem + L * 16);
    }
    #pragma unroll
    for (int it = 0; it < 5; ++it) {
      const int L = it * 256 + t;
      const int d = L >> 2, c = L & 3;
      const int cl = c ^ ((d >> 1) & 3);
      gl_lds16(Vt + ((size_t)cls * DD + d) * vtPitch + kt * 32 + cl * 8,
               smem + 20480 + L * 16);
    }
    __syncthreads();

    // ---- S^T = K @ Q^T : lane holds St[kv=st*16+lg*4+r][q=l15] ----
    floatx4 st0 = (floatx4){0.f,0.f,0.f,0.f}, st1 = (floatx4){0.f,0.f,0.f,0.f};
    #pragma unroll
    for (int kc = 0; kc < 10; ++kc) {
      const int c = kc * 4 + lg;
      const int cl = (c & ~7) | ((c & 7) ^ (l15 & 7));
      const short8 k0f = *(const short8*)(smem + l15 * 640 + cl * 16);
      const short8 k1f = *(const short8*)(smem + (16 + l15) * 640 + cl * 16);
      st0 = mfma16(k0f, qf[kc], st0);
      st1 = mfma16(k1f, qf[kc], st1);
    }

    // ---- online softmax ----
    float s[8];
    #pragma unroll
    for (int r = 0; r < 4; ++r) { s[r] = st0[r] * scale; s[4 + r] = st1[r] * scale; }
    const int kvb = kt * 32 + lg * 4;
    #pragma unroll
    for (int r = 0; r < 4; ++r) {
      if (kvb + r      >= validKV) s[r]     = -1e30f;
      if (kvb + 16 + r >= validKV) s[4 + r] = -1e30f;
    }
    float mt_ = s[0];
    #pragma unroll
    for (int i = 1; i < 8; ++i) mt_ = fmaxf(mt_, s[i]);
    mt_ = fmaxf(mt_, __shfl_xor(mt_, 16));
    mt_ = fmaxf(mt_, __shfl_xor(mt_, 32));
    const float newm = fmaxf(mrun, mt_);
    if (__any(newm > mrun)) {                     // skip-rescale when no new max
      const float alpha = __expf(mrun - newm);
      lsum *= alpha;
      #pragma unroll
      for (int i = 0; i < 20; ++i) {
        o[i][0] *= alpha; o[i][1] *= alpha; o[i][2] *= alpha; o[i][3] *= alpha;
      }
      mrun = newm;
    }
    float p[8]; float rs = 0.f;
    #pragma unroll
    for (int i = 0; i < 8; ++i) { p[i] = __expf(s[i] - mrun); rs += p[i]; }
    rs += __shfl_xor(rs, 16);
    rs += __shfl_xor(rs, 32);
    lsum += rs;

    // ---- pack P to bf16, redistribute to PV B-frag: lane needs P[q=l15][kv=8*lg+j] ----
    const unsigned int pk00 = pk2(p[0], p[1]), pk01 = pk2(p[2], p[3]);
    const unsigned int pk10 = pk2(p[4], p[5]), pk11 = pk2(p[6], p[7]);
    const int src0 = l15 + ((lane >> 4) & 1) * 32;
    const int src1 = src0 + 16;
    const int y0 = __shfl((int)pk00, src0), y1 = __shfl((int)pk01, src0);
    const int y2 = __shfl((int)pk00, src1), y3 = __shfl((int)pk01, src1);
    const int z0 = __shfl((int)pk10, src0), z1 = __shfl((int)pk11, src0);
    const int z2 = __shfl((int)pk10, src1), z3 = __shfl((int)pk11, src1);
    const bool hi = lane >= 32;                   // subtile select (kv>=16)
    union { i32x4 w; short8 v; } pf;
    pf.w[0] = hi ? z0 : y0; pf.w[1] = hi ? z1 : y1;
    pf.w[2] = hi ? z2 : y2; pf.w[3] = hi ? z3 : y3;

    // ---- O^T += Vt @ P : 20 d-tiles ----
    const int vswz = (l15 >> 1) & 3;
    #pragma unroll
    for (int dt = 0; dt < 20; ++dt) {
      const int d = dt * 16 + l15;
      const short8 a = *(const short8*)(smem + 20480 + d * 64 + ((lg ^ vswz) << 4));
      o[dt] = mfma16(a, pf.v, o[dt]);
    }
    __syncthreads();
  }

  // ---- epilogue: O^T frags -> per-wave LDS [16q][328 bf16] -> coalesced store ----
  const float invl = 1.f / lsum;
  char* ep = smem + wid * 10496;
  #pragma unroll
  for (int dt = 0; dt < 20; ++dt) {
    const unsigned int w0 = pk2(o[dt][0] * invl, o[dt][1] * invl);
    const unsigned int w1 = pk2(o[dt][2] * invl, o[dt][3] * invl);
    *(unsigned int*)(ep + l15 * 656 + (dt * 16 + lg * 4) * 2)     = w0;
    *(unsigned int*)(ep + l15 * 656 + (dt * 16 + lg * 4 + 2) * 2) = w1;
  }
  __syncthreads();
  if (wValid) {
    #pragma unroll
    for (int it = 0; it < 10; ++it) {
      const int flat = it * 64 + lane;
      const int r = flat / 40, c = flat - (flat / 40) * 40;
      const i32x4 v = *(const i32x4*)(ep + r * 656 + c * 16);
      *(i32x4*)(Ob + ((size_t)cls * qRows + qt * 16 + r) * DD + c * 8) = v;
    }
  }
}

// ---------------------------------------------------------------------------
// W [320k][320n] fp32 -> Wt [320n][320k] bf16  (tile 64x64 via LDS)
// ---------------------------------------------------------------------------
__global__ __launch_bounds__(256) void transpose_w(const float* __restrict__ W,
                                                   unsigned short* __restrict__ Wt)
{
  __shared__ float Ls[64][68];
  const int t = threadIdx.x;
  const int k0 = blockIdx.x * 64, n0 = blockIdx.y * 64;
  #pragma unroll
  for (int i = 0; i < 4; ++i) {
    const int flat = t + i * 256;
    const int r = flat >> 4, c = (flat & 15) * 4;
    *(float4*)&Ls[r][c] = *(const float4*)(W + (size_t)(k0 + r) * DD + n0 + c);
  }
  __syncthreads();
  #pragma unroll
  for (int j = 0; j < 2; ++j) {
    const int flat = t + j * 256;
    const int r2 = flat >> 3, c2 = flat & 7;
    union { unsigned short e[8]; i32x4 v; } u;
    #pragma unroll
    for (int jj = 0; jj < 8; ++jj) u.e[jj] = f2b(Ls[c2 * 8 + jj][r2]);
    *(i32x4*)(Wt + (size_t)(n0 + r2) * DD + k0 + c2 * 8) = u.v;
  }
}

// ---------------------------------------------------------------------------
// V [cls][rowsV][320] bf16 -> Vt [cls][320][vtPitch] bf16, zero-padded kv.
// grid.x = nCls * kvTilesPerCls, grid.y = 5 (d-tiles of 64)
// ---------------------------------------------------------------------------
__global__ __launch_bounds__(256) void transpose_v(
    const unsigned short* __restrict__ V, unsigned short* __restrict__ VtG,
    const int rowsV, const int vtPitch, const int kvTilesPerCls)
{
  __shared__ __align__(16) unsigned short Ls[64 * 72];
  const int t = threadIdx.x;
  const int cls = blockIdx.x / kvTilesPerCls;
  const int kvt = blockIdx.x - cls * kvTilesPerCls;
  const int dt = blockIdx.y;
  #pragma unroll
  for (int i = 0; i < 2; ++i) {
    const int flat = t + i * 256;
    const int r = flat >> 3, c = flat & 7;
    const int kv = kvt * 64 + r;
    i32x4 v = {0, 0, 0, 0};
    if (kv < rowsV)
      v = *(const i32x4*)(V + ((size_t)cls * rowsV + kv) * DD + dt * 64 + c * 8);
    *(i32x4*)(&Ls[r * 72 + c * 8]) = v;
  }
  __syncthreads();
  #pragma unroll
  for (int i = 0; i < 2; ++i) {
    const int flat = t + i * 256;
    const int r2 = flat >> 3, c2 = flat & 7;
    if (kvt * 64 + c2 * 8 < vtPitch) {
      union { unsigned short e[8]; i32x4 v; } u;
      #pragma unroll
      for (int jj = 0; jj < 8; ++jj) u.e[jj] = Ls[(c2 * 8 + jj) * 72 + r2];
      *(i32x4*)(VtG + ((size_t)cls * DD + dt * 64 + r2) * vtPitch + kvt * 64 + c2 * 8) = u.v;
    }
  }
}

// ---------------------------------------------------------------------------
// Per-row LayerNorm + logit (fp32 in), 1 wave/row.
// ---------------------------------------------------------------------------
__global__ __launch_bounds__(256) void ln_logit(
    const float* __restrict__ X, const float* __restrict__ gam,
    const float* __restrict__ bet, const float* __restrict__ Wout,
    const float* __restrict__ bout, float* __restrict__ logits, const int M)
{
  const int row = blockIdx.x * 4 + (threadIdx.x >> 6);
  if (row >= M) return;
  const int lane = threadIdx.x & 63;
  const float* x = X + (size_t)row * DD;
  float v[5]; float s = 0.f;
  #pragma unroll
  for (int i = 0; i < 5; ++i) { v[i] = x[lane + 64 * i]; s += v[i]; }
  #pragma unroll
  for (int off = 32; off; off >>= 1) s += __shfl_xor(s, off);
  const float mu = s * (1.f / DD);
  float q = 0.f;
  #pragma unroll
  for (int i = 0; i < 5; ++i) { const float d = v[i] - mu; q += d * d; }
  #pragma unroll
  for (int off = 32; off; off >>= 1) q += __shfl_xor(q, off);
  const float inv = rsqrtf(q * (1.f / DD) + LN_EPS);
  float lg = 0.f;
  #pragma unroll
  for (int i = 0; i < 5; ++i) {
    const int k = lane + 64 * i;
    lg += (gam[k] * (v[i] - mu) * inv + bet[k]) * Wout[k];
  }
  #pragma unroll
  for (int off = 32; off; off >>= 1) lg += __shfl_xor(lg, off);
  if (lane == 0) logits[row] = lg + bout[0];
}

// ---------------------------------------------------------------------------
// Final: per-class softmax over logits, weighted mean of P (bf16).
// ---------------------------------------------------------------------------
__global__ __launch_bounds__(320) void final_reduce(
    const float* __restrict__ logits_s, const float* __restrict__ logits_d,
    const unsigned short* __restrict__ Ps, const unsigned short* __restrict__ Pd,
    float* __restrict__ out)
{
  const int c = blockIdx.x;
  const int t = threadIdx.x;
  __shared__ float w[16 + ND];
  __shared__ float red[5];
  if (t < 16) w[t] = logits_s[c * 16 + t];
  for (int j = t; j < ND; j += 320) w[16 + j] = logits_d[c * ND + j];
  __syncthreads();
  if (t == 0) {
    float mx = w[0];
    #pragma unroll
    for (int i = 1; i < 16; ++i) mx = fmaxf(mx, w[i]);
    float ssum = 0.f;
    #pragma unroll
    for (int i = 0; i < 16; ++i) { const float e = __expf(w[i] - mx); w[i] = e; ssum += e; }
    const float inv = 1.f / ssum;
    #pragma unroll
    for (int i = 0; i < 16; ++i) w[i] *= inv;
  }
  float lm = -1e30f;
  for (int j = t; j < ND; j += 320) lm = fmaxf(lm, w[16 + j]);
  #pragma unroll
  for (int off = 32; off; off >>= 1) lm = fmaxf(lm, __shfl_xor(lm, off));
  if ((t & 63) == 0) red[t >> 6] = lm;
  __syncthreads();
  const float mx = fmaxf(fmaxf(fmaxf(red[0], red[1]), fmaxf(red[2], red[3])), red[4]);
  float ls = 0.f;
  for (int j = t; j < ND; j += 320) { const float e = __expf(w[16 + j] - mx); w[16 + j] = e; ls += e; }
  #pragma unroll
  for (int off = 32; off; off >>= 1) ls += __shfl_xor(ls, off);
  __syncthreads();
  if ((t & 63) == 0) red[t >> 6] = ls;
  __syncthreads();
  const float inv = 1.f / (red[0] + red[1] + red[2] + red[3] + red[4]);
  for (int j = t; j < ND; j += 320) w[16 + j] *= inv;
  __syncthreads();
  float acc = 0.f;
  const unsigned short* Psc = Ps + (size_t)c * SHOT * DD + t;
  const unsigned short* Pdc = Pd + (size_t)c * ND * DD + t;
  #pragma unroll 4
  for (int i = 0; i < 16; ++i) acc += w[i] * b2f(Psc[(size_t)i * DD]);
  for (int j = 0; j < ND; ++j) acc += w[16 + j] * b2f(Pdc[(size_t)j * DD]);
  out[c * DD + t] = acc * (1.f / 1024.f);
}

// ---------------------------------------------------------------------------
extern "C" void kernel_launch(void* const* d_in, const int* in_sizes, int n_in,
                              void* d_out, int out_size, void* d_ws, size_t ws_size,
                              hipStream_t stream)
{
  const float* xmean = (const float*)d_in[0];
  const float* x     = (const float*)d_in[1];
  const float* Wsame = (const float*)d_in[2];
  const float* bsame = (const float*)d_in[3];
  const float* Wdiff = (const float*)d_in[4];
  const float* bdiff = (const float*)d_in[5];
  const float* Wq    = (const float*)d_in[6];
  const float* bq    = (const float*)d_in[7];
  const float* Wk    = (const float*)d_in[8];
  const float* bk    = (const float*)d_in[9];
  const float* Wv    = (const float*)d_in[10];
  const float* bv    = (const float*)d_in[11];
  const float* Wfc   = (const float*)d_in[12];
  const float* bfc   = (const float*)d_in[13];
  const float* lng   = (const float*)d_in[14];
  const float* lnb   = (const float*)d_in[15];
  const float* Wout  = (const float*)d_in[16];
  const float* boutp = (const float*)d_in[17];
  float* outp = (float*)d_out;

  char* base = (char*)d_ws;
  size_t off = 0;
  auto alloc = [&](size_t bytes) { char* p = base + off; off += (bytes + 255) & ~(size_t)255; return p; };

  // fixed buffers
  unsigned short* wt[6];
  for (int i = 0; i < 6; ++i) wt[i] = (unsigned short*)alloc((size_t)DD * DD * 2);
  unsigned short* Pd_b = (unsigned short*)alloc((size_t)CC * ND * DD * 2);
  unsigned short* Ps_b = (unsigned short*)alloc((size_t)MS * DD * 2);
  unsigned short* Qs_b = (unsigned short*)alloc((size_t)MS * DD * 2);
  unsigned short* Ks_b = (unsigned short*)alloc((size_t)CC * 32 * DD * 2);
  unsigned short* Vs_b = (unsigned short*)alloc((size_t)MS * DD * 2);   // also O_same
  unsigned short* VtS  = (unsigned short*)alloc((size_t)CC * DD * 32 * 2);
  float* Fs   = (float*)alloc((size_t)MS * DD * 4);
  float* logs = (float*)alloc((size_t)MS * 4);
  float* logd = (float*)alloc((size_t)CC * ND * 4);

  // class-chunk the diff branch; CB in {64,32,16,8} keeps M%128==0
  int CB = 64;
  while (CB > 8) {
    size_t need = off;
    need += (((size_t)CB * 1024 * DD * 2) + 255 & ~(size_t)255) * 2;   // Qd, Kd
    need += (((size_t)CB * ND * DD * 2) + 255 & ~(size_t)255);          // Vd (=O)
    need += (((size_t)CB * DD * 1024 * 2) + 255 & ~(size_t)255);        // VtD
    need += (((size_t)CB * ND * DD * 4) + 255 & ~(size_t)255);          // Fd
    if (need <= ws_size) break;
    CB >>= 1;
  }
  unsigned short* Qd  = (unsigned short*)alloc((size_t)CB * 1024 * DD * 2);
  unsigned short* Kd  = (unsigned short*)alloc((size_t)CB * 1024 * DD * 2);
  unsigned short* Vd  = (unsigned short*)alloc((size_t)CB * ND * DD * 2);  // also O_diff
  unsigned short* VtD = (unsigned short*)alloc((size_t)CB * DD * 1024 * 2);
  float* Fd = (float*)alloc((size_t)CB * ND * DD * 4);

  const dim3 blk(256);
  // ---- weight transpose + bf16 cast ----
  const float* Wm[6] = {Wsame, Wdiff, Wq, Wk, Wv, Wfc};
  for (int i = 0; i < 6; ++i)
    transpose_w<<<dim3(5, 5), blk, 0, stream>>>(Wm[i], wt[i]);

  // ---- same branch ----
  {
    const dim3 g(MS / 128, 5);
    gemm_mfma<<<g, blk, 0, stream>>>(nullptr, x, xmean, 2, 0, wt[0], bsame,
                                     Ps_b, nullptr, nullptr, xmean, 16, 0, 0);
    gemm_mfma<<<g, blk, 0, stream>>>(Ps_b, nullptr, nullptr, 0, 0, wt[2], bq,
                                     Qs_b, nullptr, nullptr, nullptr, 1, 0, 0);
    gemm_mfma<<<g, blk, 0, stream>>>(Ps_b, nullptr, nullptr, 0, 0, wt[3], bk,
                                     Ks_b, nullptr, nullptr, nullptr, 1, 16, 32);
    gemm_mfma<<<g, blk, 0, stream>>>(Ps_b, nullptr, nullptr, 0, 0, wt[4], bv,
                                     Vs_b, nullptr, nullptr, nullptr, 1, 0, 0);
    transpose_v<<<dim3(CC, 5), blk, 0, stream>>>(Vs_b, VtS, 16, 32, 1);
    attn_mfma<<<dim3(CC), blk, 0, stream>>>(Qs_b, Ks_b, VtS, Vs_b,
                                            16, 16, 32, 32, 1, 16, 1, 1);
    gemm_mfma<<<g, blk, 0, stream>>>(Vs_b, nullptr, nullptr, 0, 0, wt[5], bfc,
                                     nullptr, Fs, Ps_b, nullptr, 1, 0, 0);
    ln_logit<<<dim3(MS / 4), blk, 0, stream>>>(Fs, lng, lnb, Wout, boutp, logs, MS);
  }

  // ---- diff branch, chunked ----
  for (int c0 = 0; c0 < CC; c0 += CB) {
    const int Mch = CB * ND;
    unsigned short* Pch = Pd_b + (size_t)c0 * ND * DD;
    const dim3 g(Mch / 128, 5);
    gemm_mfma<<<g, blk, 0, stream>>>(nullptr, x, xmean, 1, c0, wt[1], bdiff,
                                     Pch, nullptr, nullptr, xmean + (size_t)c0 * DD, ND, 0, 0);
    gemm_mfma<<<g, blk, 0, stream>>>(Pch, nullptr, nullptr, 0, 0, wt[2], bq,
                                     Qd, nullptr, nullptr, nullptr, 1, ND, 1024);
    gemm_mfma<<<g, blk, 0, stream>>>(Pch, nullptr, nullptr, 0, 0, wt[3], bk,
                                     Kd, nullptr, nullptr, nullptr, 1, ND, 1024);
    gemm_mfma<<<g, blk, 0, stream>>>(Pch, nullptr, nullptr, 0, 0, wt[4], bv,
                                     Vd, nullptr, nullptr, nullptr, 1, 0, 0);
    transpose_v<<<dim3(CB * 16, 5), blk, 0, stream>>>(Vd, VtD, ND, 1024, 16);
    attn_mfma<<<dim3(CB * 16), blk, 0, stream>>>(Qd, Kd, VtD, Vd,
                                                 ND, 1024, 1024, 1024, 32, ND, 16, 63);
    gemm_mfma<<<g, blk, 0, stream>>>(Vd, nullptr, nullptr, 0, 0, wt[5], bfc,
                                     nullptr, Fd, Pch, nullptr, 1, 0, 0);
    ln_logit<<<dim3(Mch / 4), blk, 0, stream>>>(Fd, lng, lnb, Wout, boutp,
                                                logd + (size_t)c0 * ND, Mch);
  }

  final_reduce<<<dim3(CC), dim3(320), 0, stream>>>(logs, logd, Ps_b, Pd_b, outp);
}

// Round 3
// 611.971 us; speedup vs baseline: 6.3876x; 1.0760x over previous
//
#include <hip/hip_runtime.h>

#define CC   64
#define SHOT 16
#define DD   320
#define ND   1008            // (CC-1)*SHOT
#define MS   (CC * SHOT)     // 1024
#define LN_EPS 1e-5f

typedef __attribute__((ext_vector_type(8)))  short short8;    // 8 bf16 = 4 VGPR
typedef __attribute__((ext_vector_type(4)))  float floatx4;
typedef __attribute__((ext_vector_type(16))) float floatx16;
typedef __attribute__((ext_vector_type(4)))  int i32x4;

__device__ __forceinline__ unsigned short f2b(float f) {     // fp32 -> bf16 RNE
  union { float f; unsigned int u; } v; v.f = f;
  unsigned int r = v.u + 0x7FFFu + ((v.u >> 16) & 1u);
  return (unsigned short)(r >> 16);
}
__device__ __forceinline__ float b2f(unsigned short b) {
  union { unsigned int u; float f; } v; v.u = ((unsigned int)b) << 16; return v.f;
}
__device__ __forceinline__ unsigned int pk2(float a, float b) {
  return (unsigned int)f2b(a) | ((unsigned int)f2b(b) << 16);
}
__device__ __forceinline__ void gl_lds16(const void* g, void* l) {
  __builtin_amdgcn_global_load_lds(
      (const __attribute__((address_space(1))) unsigned int*)g,
      (__attribute__((address_space(3))) unsigned int*)l, 16, 0, 0);
}
__device__ __forceinline__ floatx4 mfma16(short8 a, short8 b, floatx4 c) {
  return __builtin_amdgcn_mfma_f32_16x16x32_bf16(a, b, c, 0, 0, 0);
}
__device__ __forceinline__ floatx16 mfma32(short8 a, short8 b, floatx16 c) {
  return __builtin_amdgcn_mfma_f32_32x32x16_bf16(a, b, c, 0, 0, 0);
}
#define BARRIER_VM()  do { asm volatile("s_waitcnt vmcnt(0) lgkmcnt(0)" ::: "memory"); \
                           __builtin_amdgcn_s_barrier(); \
                           __builtin_amdgcn_sched_barrier(0); } while (0)

// ---------------------------------------------------------------------------
// MFMA GEMM: Out[M x 320] = A[M x 320] @ W   (Bt = W^T bf16 [320n][320k])
// BM=128 BN=64 BK=64, 4 waves (2x2). mode0: A bf16; mode1: A=xmean[c]-x[gather];
// mode2: A=x[m]-xmean[m/16].  Epilogue: +bias[n], -msMean[(m/msRpc)][n],
// +ResB[m][n] (bf16); writes OutB (bf16 row-major) and/or
// OutT (bf16 transposed per class: OutT[(m/tRpc)*320 + n][tPitch] at col m%tRpc).
// ---------------------------------------------------------------------------
__global__ __launch_bounds__(256, 2) void gemm_mfma(
    const unsigned short* __restrict__ A,
    const float* __restrict__ Xg, const float* __restrict__ Xmean,
    const int mode, const int c0,
    const unsigned short* __restrict__ Bt,
    const float* __restrict__ bias,
    unsigned short* __restrict__ OutB,
    unsigned short* __restrict__ OutT, const int tRpc, const int tPitch,
    const unsigned short* __restrict__ ResB,
    const float* __restrict__ msMean, const int msRpc)
{
  __shared__ __align__(16) unsigned short As[2][128 * 64];
  __shared__ __align__(16) unsigned short Bs[2][64 * 64];
  const int t  = threadIdx.x;
  const int m0 = blockIdx.x * 128;
  const int n0 = blockIdx.y * 64;
  const int wid = t >> 6, lane = t & 63;
  const int wm = wid >> 1, wn = wid & 1;
  const int l15 = lane & 15, lg = lane >> 4;

  const int ra = t >> 1, kh = t & 1;
  const float* aptr = nullptr; const float* mptr = nullptr;
  if (mode == 1) {
    const int am = m0 + ra;
    const int lc = am / ND, j = am - lc * ND;
    const int c  = c0 + lc;
    const int oi = j >> 4, s = j & 15;
    const int oc = (oi < c) ? oi : oi + 1;
    aptr = Xg + (size_t)(oc * SHOT + s) * DD;
    mptr = Xmean + (size_t)c * DD;
  } else if (mode == 2) {
    aptr = Xg + (size_t)(m0 + ra) * DD;
    mptr = Xmean + (size_t)((m0 + ra) >> 4) * DD;
  }

  floatx4 acc[4][2];
  #pragma unroll
  for (int i = 0; i < 4; ++i)
    #pragma unroll
    for (int j = 0; j < 2; ++j) acc[i][j] = (floatx4){0.f, 0.f, 0.f, 0.f};

  auto stage = [&](int ks, int bufi) {
    const int k0 = ks * 64;
    #pragma unroll
    for (int it = 0; it < 2; ++it) {               // B tile 64x64
      const int L = it * 256 + t;
      const int r = L >> 3, cs = L & 7;
      const int cl = cs ^ (r & 7);
      gl_lds16(Bt + (size_t)(n0 + r) * DD + k0 + cl * 8, &Bs[bufi][0] + L * 8);
    }
    if (mode == 0) {
      #pragma unroll
      for (int it = 0; it < 4; ++it) {             // A tile 128x64
        const int L = it * 256 + t;
        const int r = L >> 3, cs = L & 7;
        const int cl = cs ^ (r & 7);
        gl_lds16(A + (size_t)(m0 + r) * DD + k0 + cl * 8, &As[bufi][0] + L * 8);
      }
    } else {
      const float sa = (mode == 1) ? -1.f : 1.f;
      const int kb2 = k0 + kh * 32;
      #pragma unroll
      for (int i = 0; i < 4; ++i) {
        const float4 x0  = *(const float4*)(aptr + kb2 + i * 8);
        const float4 x1  = *(const float4*)(aptr + kb2 + i * 8 + 4);
        const float4 mv0 = *(const float4*)(mptr + kb2 + i * 8);
        const float4 mv1 = *(const float4*)(mptr + kb2 + i * 8 + 4);
        i32x4 w;
        w[0] = (int)pk2(sa * (x0.x - mv0.x), sa * (x0.y - mv0.y));
        w[1] = (int)pk2(sa * (x0.z - mv0.z), sa * (x0.w - mv0.w));
        w[2] = (int)pk2(sa * (x1.x - mv1.x), sa * (x1.y - mv1.y));
        w[3] = (int)pk2(sa * (x1.z - mv1.z), sa * (x1.w - mv1.w));
        const int c  = kh * 4 + i;
        const int cw = c ^ (ra & 7);
        *(i32x4*)((char*)&As[bufi][0] + ra * 128 + cw * 16) = w;
      }
    }
  };

  auto compute = [&](int bufi) {
    #pragma unroll
    for (int kc = 0; kc < 2; ++kc) {
      short8 af[4], bf[2];
      #pragma unroll
      for (int mt = 0; mt < 4; ++mt) {
        const int row = wm * 64 + mt * 16 + l15;
        const int cs  = (kc * 4 + lg) ^ (row & 7);
        af[mt] = *(const short8*)((const char*)&As[bufi][0] + row * 128 + cs * 16);
      }
      #pragma unroll
      for (int nt = 0; nt < 2; ++nt) {
        const int row = wn * 32 + nt * 16 + l15;
        const int cs  = (kc * 4 + lg) ^ (row & 7);
        bf[nt] = *(const short8*)((const char*)&Bs[bufi][0] + row * 128 + cs * 16);
      }
      #pragma unroll
      for (int mt = 0; mt < 4; ++mt)
        #pragma unroll
        for (int nt = 0; nt < 2; ++nt)
          acc[mt][nt] = mfma16(af[mt], bf[nt], acc[mt][nt]);
    }
  };

  stage(0, 0);
  BARRIER_VM();
  for (int ks = 0; ks < 5; ++ks) {
    if (ks + 1 < 5) stage(ks + 1, (ks + 1) & 1);
    compute(ks & 1);
    BARRIER_VM();
  }

  // epilogue: C[row=(lane>>4)*4+r][col=lane&15]
  #pragma unroll
  for (int nt = 0; nt < 2; ++nt) {
    const int n = n0 + wn * 32 + nt * 16 + l15;
    const float bb = bias[n];
    #pragma unroll
    for (int mt = 0; mt < 4; ++mt) {
      #pragma unroll
      for (int r = 0; r < 4; ++r) {
        const int m = m0 + wm * 64 + mt * 16 + lg * 4 + r;
        float v = acc[mt][nt][r] + bb;
        if (msMean) v -= msMean[(size_t)(m / msRpc) * DD + n];
        if (ResB)   v += b2f(ResB[(size_t)m * DD + n]);
        const unsigned short bv = f2b(v);
        if (OutB) OutB[(size_t)m * DD + n] = bv;
        if (OutT) {
          const int cm = m / tRpc, kv = m - cm * tRpc;
          OutT[((size_t)cm * DD + n) * tPitch + kv] = bv;
        }
      }
    }
  }
}

// ---------------------------------------------------------------------------
// 32x32 MFMA flash attention (swapped QK^T, V = P via P^T buffer).
// Block = 4 waves x 32 q-rows; kv-tile 32; double-buffered K/V LDS staging.
// S^T = mfma32(Kfrag, Qfrag); softmax reduce: 16 regs + shfl_xor(32);
// defer-max rescale (THR=8); P->bf16 + xor32 exchange -> PV B-frag;
// O^T = mfma32(Ptfrag, Pfrag). 1 block/CU (LDS 84KB), VGPR-rich.
// ---------------------------------------------------------------------------
__global__ __launch_bounds__(256, 1) void attn32(
    const unsigned short* __restrict__ Qg, const unsigned short* __restrict__ Pk,
    const unsigned short* __restrict__ Pt, unsigned short* __restrict__ Ob,
    const int qRows,      // rows per class (out + Q in): 1008 | 16
    const int kRows,      // rows per class in Pk: 1008 | 16
    const int vtPitch,    // P^T kv pitch: 1024 | 32
    const int validKV, const int nKT, const int qTPC, const int swzQ8)
{
  __shared__ __align__(16) char smem[83968];   // 2x40960 staging | 4x20992 epilogue
  const int t = threadIdx.x;
  const int wid = t >> 6, lane = t & 63;
  const int l31 = lane & 31, hi = lane >> 5;
  const int hi4 = hi * 4, hi8 = hi * 8;

  int cls, bI;
  if (swzQ8 > 0) {                      // group a class's blocks on one XCD
    const int X = blockIdx.x & 7, Y = blockIdx.x >> 3;
    cls = X + 8 * (Y % swzQ8);
    bI  = Y / swzQ8;
  } else { cls = blockIdx.x; bI = 0; }
  const int qt0 = bI * 4 + wid;
  const bool wValid = qt0 < qTPC;
  const int qt = wValid ? qt0 : 0;

  // Q fragments (B operand): lane holds Q[q = l31][d = ks*16 + hi*8 + j]
  short8 qf[20];
  {
    const unsigned short* qrow = Qg + ((size_t)cls * qRows + qt * 32 + l31) * DD;
    #pragma unroll
    for (int ks = 0; ks < 20; ++ks) qf[ks] = *(const short8*)(qrow + ks * 16 + hi8);
  }

  floatx16 o[10];
  #pragma unroll
  for (int dt = 0; dt < 10; ++dt) o[dt] = (floatx16)(0.f);
  float mrun = -3.0e38f, lsum = 0.f;
  const float scale = 0.05590169943749474f;   // 1/sqrt(320)

  auto stage = [&](int kt, int bufb) {
    char* kb = smem + bufb * 40960;
    #pragma unroll
    for (int it = 0; it < 5; ++it) {            // K tile [32 kv][320 d]
      const int L = it * 256 + t;
      const int kv = L / 40, c = L - kv * 40;
      const int g = (c & ~7) | ((c & 7) ^ (kv & 7));
      gl_lds16(Pk + ((size_t)(cls * kRows + kt * 32 + kv)) * DD + g * 8, kb + L * 16);
    }
    #pragma unroll
    for (int it = 0; it < 5; ++it) {            // V tile = P^T [320 d][32 kv]
      const int L = it * 256 + t;
      const int d = L >> 2, c = L & 3;
      const int g = c ^ ((d >> 1) & 3);
      gl_lds16(Pt + ((size_t)(cls * DD + d)) * vtPitch + kt * 32 + g * 8,
               kb + 20480 + L * 16);
    }
  };

  stage(0, 0);
  BARRIER_VM();
  int cb = 0;
  for (int kt = 0; kt < nKT; ++kt) {
    if (kt + 1 < nKT) stage(kt + 1, cb ^ 1);
    const char* kb = smem + cb * 40960;

    // ---- S^T = K @ Q^T (two interleaved chains) ----
    floatx16 sta = (floatx16)(0.f), stb = (floatx16)(0.f);
    #pragma unroll
    for (int ks = 0; ks < 20; ks += 2) {
      const int ca = 2 * ks + hi;
      const int cla = (ca & ~7) | ((ca & 7) ^ (l31 & 7));
      const short8 kfa = *(const short8*)(kb + l31 * 640 + cla * 16);
      sta = mfma32(kfa, qf[ks], sta);
      const int cbx = 2 * (ks + 1) + hi;
      const int clb = (cbx & ~7) | ((cbx & 7) ^ (l31 & 7));
      const short8 kfb = *(const short8*)(kb + l31 * 640 + clb * 16);
      stb = mfma32(kfb, qf[ks + 1], stb);
    }

    // ---- online softmax over 32 kv rows (16 regs + xor-32 partner) ----
    float s[16];
    #pragma unroll
    for (int i = 0; i < 16; ++i) s[i] = (sta[i] + stb[i]) * scale;
    if (kt == nKT - 1) {
      #pragma unroll
      for (int i = 0; i < 16; ++i) {
        const int row = (i & 3) + 8 * (i >> 2) + hi4;
        if (kt * 32 + row >= validKV) s[i] = -1e30f;
      }
    }
    float mt_ = s[0];
    #pragma unroll
    for (int i = 1; i < 16; ++i) mt_ = fmaxf(mt_, s[i]);
    mt_ = fmaxf(mt_, __shfl_xor(mt_, 32));
    if (!__all(mt_ - mrun <= 8.0f)) {           // defer-max (T13)
      const float newm = fmaxf(mrun, mt_);
      const float alpha = __expf(mrun - newm);
      lsum *= alpha;
      #pragma unroll
      for (int dt = 0; dt < 10; ++dt)
        #pragma unroll
        for (int i = 0; i < 16; ++i) o[dt][i] *= alpha;
      mrun = newm;
    }
    float rs = 0.f;
    #pragma unroll
    for (int i = 0; i < 16; ++i) { s[i] = __expf(s[i] - mrun); rs += s[i]; }
    rs += __shfl_xor(rs, 32);
    lsum += rs;

    // ---- pack P -> bf16 PV B-fragments ----
    unsigned int pk[8], ow[8];
    #pragma unroll
    for (int a = 0; a < 8; ++a) pk[a] = pk2(s[2 * a], s[2 * a + 1]);
    #pragma unroll
    for (int a = 0; a < 8; ++a) ow[a] = (unsigned int)__shfl_xor((int)pk[a], 32);
    union { i32x4 w; short8 v; } bf0, bf1;
    bf0.w[0] = (int)(hi ? ow[2] : pk[0]); bf0.w[1] = (int)(hi ? ow[3] : pk[1]);
    bf0.w[2] = (int)(hi ? pk[2] : ow[0]); bf0.w[3] = (int)(hi ? pk[3] : ow[1]);
    bf1.w[0] = (int)(hi ? ow[6] : pk[4]); bf1.w[1] = (int)(hi ? ow[7] : pk[5]);
    bf1.w[2] = (int)(hi ? pk[6] : ow[4]); bf1.w[3] = (int)(hi ? pk[7] : ow[5]);

    // ---- O^T += P^T_tile @ P : 10 d-tiles x 2 k-slices ----
    const char* vb = kb + 20480;
    const int vx = (l31 >> 1) & 3;
    #pragma unroll
    for (int dt = 0; dt < 10; ++dt) {
      const short8 a0 = *(const short8*)(vb + (dt * 32 + l31) * 64 + ((hi ^ vx) << 4));
      o[dt] = mfma32(a0, bf0.v, o[dt]);
    }
    #pragma unroll
    for (int dt = 0; dt < 10; ++dt) {
      const short8 a1 = *(const short8*)(vb + (dt * 32 + l31) * 64 + (((2 + hi) ^ vx) << 4));
      o[dt] = mfma32(a1, bf1.v, o[dt]);
    }

    BARRIER_VM();
    cb ^= 1;
  }

  // ---- epilogue: O^T frags -> per-wave LDS [32 q][328 bf16] -> coalesced ----
  const float invl = 1.f / lsum;
  char* ep = smem + wid * 20992;
  #pragma unroll
  for (int dt = 0; dt < 10; ++dt) {
    #pragma unroll
    for (int g = 0; g < 4; ++g) {
      #pragma unroll
      for (int b2 = 0; b2 < 2; ++b2) {
        const int r0 = g * 4 + b2 * 2;
        const unsigned int w = pk2(o[dt][r0] * invl, o[dt][r0 + 1] * invl);
        *(unsigned int*)(ep + l31 * 656 + (dt * 32 + 8 * g + hi4 + 2 * b2) * 2) = w;
      }
    }
  }
  __syncthreads();
  if (wValid) {
    #pragma unroll
    for (int it = 0; it < 20; ++it) {
      const int flat = it * 64 + lane;
      const int q = flat / 40, c = flat - (flat / 40) * 40;
      if (qt * 32 + q < qRows) {
        const i32x4 v = *(const i32x4*)(ep + q * 656 + c * 16);
        *(i32x4*)(Ob + ((size_t)(cls * qRows + qt * 32 + q)) * DD + c * 8) = v;
      }
    }
  }
}

// ---------------------------------------------------------------------------
// W [320k][320n] fp32 -> Wt [320n][320k] bf16
// ---------------------------------------------------------------------------
__global__ __launch_bounds__(256) void transpose_w(const float* __restrict__ W,
                                                   unsigned short* __restrict__ Wt)
{
  __shared__ float Ls[64][68];
  const int t = threadIdx.x;
  const int k0 = blockIdx.x * 64, n0 = blockIdx.y * 64;
  #pragma unroll
  for (int i = 0; i < 4; ++i) {
    const int flat = t + i * 256;
    const int r = flat >> 4, c = (flat & 15) * 4;
    *(float4*)&Ls[r][c] = *(const float4*)(W + (size_t)(k0 + r) * DD + n0 + c);
  }
  __syncthreads();
  #pragma unroll
  for (int j = 0; j < 2; ++j) {
    const int flat = t + j * 256;
    const int r2 = flat >> 3, c2 = flat & 7;
    union { unsigned short e[8]; i32x4 v; } u;
    #pragma unroll
    for (int jj = 0; jj < 8; ++jj) u.e[jj] = f2b(Ls[c2 * 8 + jj][r2]);
    *(i32x4*)(Wt + (size_t)(n0 + r2) * DD + k0 + c2 * 8) = u.v;
  }
}

// ---------------------------------------------------------------------------
// Weight product: Bt[n][k] = sum_m L'[n][m] * R[k][m], L'[n][m] = trL?L[m][n]:L[n][m]
// Used for Bt_G = (Wq Wk^T)^T and Bt_vf = (Wv Wfc)^T, bf16 output.
// ---------------------------------------------------------------------------
__global__ __launch_bounds__(256) void wprod(const float* __restrict__ L,
                                             const float* __restrict__ R,
                                             const int trL,
                                             unsigned short* __restrict__ Bt)
{
  __shared__ float Lsm[16][68];
  __shared__ float Rsm[16][68];
  const int t = threadIdx.x;
  const int n0 = blockIdx.x * 64, k0 = blockIdx.y * 64;
  const int tn4 = (t & 15) * 4, tk4 = (t >> 4) * 4;
  float acc[4][4] = {};
  for (int ms = 0; ms < DD; ms += 16) {
    const int lr = t >> 4, lc = (t & 15);        // 16 rows x 16 cols(x4)
    #pragma unroll
    for (int i = 0; i < 4; ++i) {
      const int nn = lc * 4 + i;
      Lsm[lr][nn] = trL ? L[(size_t)(ms + lr) * DD + n0 + nn]
                        : L[(size_t)(n0 + nn) * DD + ms + lr];
      Rsm[lr][nn] = R[(size_t)(k0 + nn) * DD + ms + lr];
    }
    __syncthreads();
    #pragma unroll
    for (int mm = 0; mm < 16; ++mm) {
      float la[4], rb[4];
      #pragma unroll
      for (int i = 0; i < 4; ++i) { la[i] = Lsm[mm][tn4 + i]; rb[i] = Rsm[mm][tk4 + i]; }
      #pragma unroll
      for (int i = 0; i < 4; ++i)
        #pragma unroll
        for (int j = 0; j < 4; ++j) acc[i][j] += la[i] * rb[j];
    }
    __syncthreads();
  }
  #pragma unroll
  for (int i = 0; i < 4; ++i)
    #pragma unroll
    for (int j = 0; j < 4; ++j)
      Bt[(size_t)(n0 + tn4 + i) * DD + k0 + tk4 + j] = f2b(acc[i][j]);
}

// v[n] = sum_m Wk[n,m] bq[m];  bvf[n] = sum_m Wfc[m,n] bv[m] + bfc[n]
__global__ __launch_bounds__(640) void wbias(
    const float* __restrict__ Wk, const float* __restrict__ bq,
    const float* __restrict__ Wfc, const float* __restrict__ bv,
    const float* __restrict__ bfc, float* __restrict__ v, float* __restrict__ bvf)
{
  const int t = threadIdx.x;
  if (t < DD) {
    float a = 0.f;
    for (int m = 0; m < DD; ++m) a += Wk[(size_t)t * DD + m] * bq[m];
    v[t] = a;
  } else if (t < 2 * DD) {
    const int n = t - DD;
    float a = 0.f;
    for (int m = 0; m < DD; ++m) a += Wfc[(size_t)m * DD + n] * bv[m];
    bvf[n] = a + bfc[n];
  }
}

// ---------------------------------------------------------------------------
// Per-row LayerNorm + logit (bf16 in), 1 wave/row.
// ---------------------------------------------------------------------------
__global__ __launch_bounds__(256) void ln_logit(
    const unsigned short* __restrict__ X, const float* __restrict__ gam,
    const float* __restrict__ bet, const float* __restrict__ Wout,
    const float* __restrict__ bout, float* __restrict__ logits, const int M)
{
  const int row = blockIdx.x * 4 + (threadIdx.x >> 6);
  if (row >= M) return;
  const int lane = threadIdx.x & 63;
  const unsigned short* x = X + (size_t)row * DD;
  float v[5]; float s = 0.f;
  #pragma unroll
  for (int i = 0; i < 5; ++i) { v[i] = b2f(x[lane + 64 * i]); s += v[i]; }
  #pragma unroll
  for (int off = 32; off; off >>= 1) s += __shfl_xor(s, off);
  const float mu = s * (1.f / DD);
  float q = 0.f;
  #pragma unroll
  for (int i = 0; i < 5; ++i) { const float d = v[i] - mu; q += d * d; }
  #pragma unroll
  for (int off = 32; off; off >>= 1) q += __shfl_xor(q, off);
  const float inv = rsqrtf(q * (1.f / DD) + LN_EPS);
  float lg = 0.f;
  #pragma unroll
  for (int i = 0; i < 5; ++i) {
    const int k = lane + 64 * i;
    lg += (gam[k] * (v[i] - mu) * inv + bet[k]) * Wout[k];
  }
  #pragma unroll
  for (int off = 32; off; off >>= 1) lg += __shfl_xor(lg, off);
  if (lane == 0) logits[row] = lg + bout[0];
}

// ---------------------------------------------------------------------------
// Final: per-class softmax over logits, weighted mean of P (bf16).
// ---------------------------------------------------------------------------
__global__ __launch_bounds__(320) void final_reduce(
    const float* __restrict__ logits_s, const float* __restrict__ logits_d,
    const unsigned short* __restrict__ Ps, const unsigned short* __restrict__ Pd,
    float* __restrict__ out)
{
  const int c = blockIdx.x;
  const int t = threadIdx.x;
  __shared__ float w[16 + ND];
  __shared__ float red[5];
  if (t < 16) w[t] = logits_s[c * 16 + t];
  for (int j = t; j < ND; j += 320) w[16 + j] = logits_d[c * ND + j];
  __syncthreads();
  if (t == 0) {
    float mx = w[0];
    #pragma unroll
    for (int i = 1; i < 16; ++i) mx = fmaxf(mx, w[i]);
    float ssum = 0.f;
    #pragma unroll
    for (int i = 0; i < 16; ++i) { const float e = __expf(w[i] - mx); w[i] = e; ssum += e; }
    const float inv = 1.f / ssum;
    #pragma unroll
    for (int i = 0; i < 16; ++i) w[i] *= inv;
  }
  float lm = -1e30f;
  for (int j = t; j < ND; j += 320) lm = fmaxf(lm, w[16 + j]);
  #pragma unroll
  for (int off = 32; off; off >>= 1) lm = fmaxf(lm, __shfl_xor(lm, off));
  if ((t & 63) == 0) red[t >> 6] = lm;
  __syncthreads();
  const float mx = fmaxf(fmaxf(fmaxf(red[0], red[1]), fmaxf(red[2], red[3])), red[4]);
  float ls = 0.f;
  for (int j = t; j < ND; j += 320) { const float e = __expf(w[16 + j] - mx); w[16 + j] = e; ls += e; }
  #pragma unroll
  for (int off = 32; off; off >>= 1) ls += __shfl_xor(ls, off);
  __syncthreads();
  if ((t & 63) == 0) red[t >> 6] = ls;
  __syncthreads();
  const float inv = 1.f / (red[0] + red[1] + red[2] + red[3] + red[4]);
  for (int j = t; j < ND; j += 320) w[16 + j] *= inv;
  __syncthreads();
  float acc = 0.f;
  const unsigned short* Psc = Ps + (size_t)c * SHOT * DD + t;
  const unsigned short* Pdc = Pd + (size_t)c * ND * DD + t;
  #pragma unroll 4
  for (int i = 0; i < 16; ++i) acc += w[i] * b2f(Psc[(size_t)i * DD]);
  for (int j = 0; j < ND; ++j) acc += w[16 + j] * b2f(Pdc[(size_t)j * DD]);
  out[c * DD + t] = acc * (1.f / 1024.f);
}

// ---------------------------------------------------------------------------
extern "C" void kernel_launch(void* const* d_in, const int* in_sizes, int n_in,
                              void* d_out, int out_size, void* d_ws, size_t ws_size,
                              hipStream_t stream)
{
  const float* xmean = (const float*)d_in[0];
  const float* x     = (const float*)d_in[1];
  const float* Wsame = (const float*)d_in[2];
  const float* bsame = (const float*)d_in[3];
  const float* Wdiff = (const float*)d_in[4];
  const float* bdiff = (const float*)d_in[5];
  const float* Wq    = (const float*)d_in[6];
  const float* bq    = (const float*)d_in[7];
  const float* Wk    = (const float*)d_in[8];
  const float* bk    = (const float*)d_in[9];   (void)bk; // dropped: row-const in softmax
  const float* Wv    = (const float*)d_in[10];
  const float* bv    = (const float*)d_in[11];
  const float* Wfc   = (const float*)d_in[12];
  const float* bfc   = (const float*)d_in[13];
  const float* lng   = (const float*)d_in[14];
  const float* lnb   = (const float*)d_in[15];
  const float* Wout  = (const float*)d_in[16];
  const float* boutp = (const float*)d_in[17];
  float* outp = (float*)d_out;

  char* base = (char*)d_ws;
  size_t off = 0;
  auto alloc = [&](size_t bytes) { char* p = base + off; off += (bytes + 255) & ~(size_t)255; return p; };

  const size_t WB = (size_t)DD * DD * 2;
  unsigned short* BtS  = (unsigned short*)alloc(WB);
  unsigned short* BtD  = (unsigned short*)alloc(WB);
  unsigned short* BtG  = (unsigned short*)alloc(WB);
  unsigned short* BtVF = (unsigned short*)alloc(WB);
  float* vbias = (float*)alloc(DD * 4);
  float* bvf   = (float*)alloc(DD * 4);
  unsigned short* Pd_b = (unsigned short*)alloc((size_t)(CC * ND + 64) * DD * 2);
  unsigned short* Ps_b = (unsigned short*)alloc((size_t)(MS + 64) * DD * 2);
  unsigned short* PtS  = (unsigned short*)alloc((size_t)CC * DD * 32 * 2);
  unsigned short* Qgs  = (unsigned short*)alloc((size_t)(MS + 64) * DD * 2);  // also F_same
  unsigned short* Os_b = (unsigned short*)alloc((size_t)MS * DD * 2);
  float* logs = (float*)alloc((size_t)MS * 4);
  float* logd = (float*)alloc((size_t)CC * ND * 4);

  // class-chunk the diff branch; CB in {64,32,16,8}
  int CB = 64;
  while (CB > 8) {
    size_t need = off;
    need += ((size_t)CB * DD * 1024 * 2 + 255 & ~(size_t)255);          // PtD
    need += ((size_t)(CB * ND + 64) * DD * 2 + 255 & ~(size_t)255);     // Qgd (=F)
    need += ((size_t)CB * ND * DD * 2 + 255 & ~(size_t)255);            // Od
    if (need <= ws_size) break;
    CB >>= 1;
  }
  unsigned short* PtD = (unsigned short*)alloc((size_t)CB * DD * 1024 * 2);
  unsigned short* Qgd = (unsigned short*)alloc((size_t)(CB * ND + 64) * DD * 2);
  unsigned short* Od  = (unsigned short*)alloc((size_t)CB * ND * DD * 2);

  const dim3 blk(256);
  // ---- weight prep ----
  transpose_w<<<dim3(5, 5), blk, 0, stream>>>(Wsame, BtS);
  transpose_w<<<dim3(5, 5), blk, 0, stream>>>(Wdiff, BtD);
  wprod<<<dim3(5, 5), blk, 0, stream>>>(Wk, Wq, 0, BtG);    // Bt_G[n][k]=sum Wk[n,m]Wq[k,m]
  wprod<<<dim3(5, 5), blk, 0, stream>>>(Wfc, Wv, 1, BtVF);  // Bt_vf[n][k]=sum Wfc[m,n]Wv[k,m]
  wbias<<<dim3(1), dim3(640), 0, stream>>>(Wk, bq, Wfc, bv, bfc, vbias, bvf);

  // ---- same branch ----
  {
    const dim3 g(MS / 128, 5);
    gemm_mfma<<<g, blk, 0, stream>>>(nullptr, x, xmean, 2, 0, BtS, bsame,
                                     Ps_b, PtS, 16, 32, nullptr, xmean, 16);
    gemm_mfma<<<g, blk, 0, stream>>>(Ps_b, nullptr, nullptr, 0, 0, BtG, vbias,
                                     Qgs, nullptr, 1, 1, nullptr, nullptr, 1);
    attn32<<<dim3(CC), blk, 0, stream>>>(Qgs, Ps_b, PtS, Os_b, 16, 16, 32, 16, 1, 1, 0);
    gemm_mfma<<<g, blk, 0, stream>>>(Os_b, nullptr, nullptr, 0, 0, BtVF, bvf,
                                     Qgs, nullptr, 1, 1, Ps_b, nullptr, 1);
    ln_logit<<<dim3(MS / 4), blk, 0, stream>>>(Qgs, lng, lnb, Wout, boutp, logs, MS);
  }

  // ---- diff branch, chunked ----
  for (int c0 = 0; c0 < CC; c0 += CB) {
    const int Mch = CB * ND;
    unsigned short* Pch = Pd_b + (size_t)c0 * ND * DD;
    const dim3 g(Mch / 128, 5);
    gemm_mfma<<<g, blk, 0, stream>>>(nullptr, x, xmean, 1, c0, BtD, bdiff,
                                     Pch, PtD, ND, 1024, nullptr,
                                     xmean + (size_t)c0 * DD, ND);
    gemm_mfma<<<g, blk, 0, stream>>>(Pch, nullptr, nullptr, 0, 0, BtG, vbias,
                                     Qgd, nullptr, 1, 1, nullptr, nullptr, 1);
    attn32<<<dim3(CB * 8), blk, 0, stream>>>(Qgd, Pch, PtD, Od,
                                             ND, ND, 1024, ND, 32, 32, CB >> 3);
    gemm_mfma<<<g, blk, 0, stream>>>(Od, nullptr, nullptr, 0, 0, BtVF, bvf,
                                     Qgd, nullptr, 1, 1, Pch, nullptr, 1);
    ln_logit<<<dim3(Mch / 4), blk, 0, stream>>>(Qgd, lng, lnb, Wout, boutp,
                                                logd + (size_t)c0 * ND, Mch);
  }

  final_reduce<<<dim3(CC), dim3(320), 0, stream>>>(logs, logd, Ps_b, Pd_b, outp);
}